// Round 2
// baseline (2453.459 us; speedup 1.0000x reference)
//
#include <hip/hip_runtime.h>
#include <math.h>

#define H   128
#define G4  512   // 4*H
#define TT  128   // timesteps
#define BB  8     // batch

__device__ __forceinline__ float sigf(float x)      { return 1.0f / (1.0f + __expf(-x)); }
__device__ __forceinline__ float tanhf_fast(float x){ return 1.0f - 2.0f / (1.0f + __expf(2.0f * x)); }

// ---------------------------------------------------------------------------
// prep: transpose w_ih1 (full) and w_hh1 cols 64..127 into [k4][r] float4
// layout so streamed / LDS-staged loads are lane-coalesced.
// ---------------------------------------------------------------------------
__global__ void prep_kernel(const float* __restrict__ w_ih1,
                            const float* __restrict__ w_hh1,
                            float4* __restrict__ ws4) {
    int id = blockIdx.x * 256 + threadIdx.x;    // 0 .. 24575
    if (id < 16384) {
        int k4 = id >> 9, r = id & 511;
        ws4[k4 * 512 + r] = *reinterpret_cast<const float4*>(w_ih1 + r * H + k4 * 4);
    } else {
        int id2 = id - 16384;
        int k4 = id2 >> 9, r = id2 & 511;       // k4: 0..15 -> cols 64..127
        ws4[16384 + k4 * 512 + r] =
            *reinterpret_cast<const float4*>(w_hh1 + r * H + 64 + k4 * 4);
    }
}

// ---------------------------------------------------------------------------
// main: one block (CU) per batch, 512 threads = one per gate row.
// Weight residency: w_hh0 full + w_hh1[:, :64] in registers,
// w_hh1[:, 64:] in LDS (transposed, conflict-free b128), w_ih1 streamed
// from L2 each step with 8-deep register prefetch issued at step start.
// ---------------------------------------------------------------------------
__global__ __launch_bounds__(512, 2)
void lstm_kernel(const float* __restrict__ x,
                 const float* __restrict__ w_ih0,
                 const float* __restrict__ w_hh0,
                 const float* __restrict__ w_hh1,
                 const float* __restrict__ b_ih0,
                 const float* __restrict__ b_hh0,
                 const float* __restrict__ b_ih1,
                 const float* __restrict__ b_hh1,
                 const float* __restrict__ w_out,
                 const float4* __restrict__ wiT4,   // [32][512] transposed w_ih1
                 const float4* __restrict__ whT4,   // [16][512] transposed w_hh1 cols 64..127
                 float* __restrict__ gbuf) {
    __shared__ float4 whh1b[16 * 512];   // 128 KB: w_hh1 cols 64..127, [k4][r]
    __shared__ float4 h1s4[H / 4];
    __shared__ float4 h2s4[H / 4];
    __shared__ float4 vs4[H / 4];
    __shared__ float  act1[G4], da1[G4], act2[G4], t2[G4];
    __shared__ float  u_s[TT];
    __shared__ float  red[2];

    float* h1s = (float*)h1s4;
    float* h2s = (float*)h2s4;
    float* vs  = (float*)vs4;

    const int b = blockIdx.x;
    const int r = threadIdx.x;

    const float wcol  = w_ih0[r];             // w_ih0 is [512,1]
    const float bias0 = b_ih0[r] + b_hh0[r];
    const float bias1 = b_ih1[r] + b_hh1[r];
    const bool  is_g  = (r >= 256) && (r < 384);   // wave-uniform (gate blocks of 128)

    // register-resident weights: w_hh0 row r (32 f4), w_hh1 row r cols 0..63 (16 f4)
    float4 wh0[32], wh1a[16];
    {
        const float4* p0 = reinterpret_cast<const float4*>(w_hh0 + r * H);
#pragma unroll
        for (int q = 0; q < 32; q++) wh0[q] = p0[q];
        const float4* p1 = reinterpret_cast<const float4*>(w_hh1 + r * H);
#pragma unroll
        for (int q = 0; q < 16; q++) wh1a[q] = p1[q];
    }

    // stage w_hh1 cols 64..127 (transposed) into LDS — coalesced, conflict-free
#pragma unroll
    for (int q = 0; q < 16; q++) whh1b[q * 512 + r] = whT4[q * 512 + r];

    float c1 = 0.f, c2 = 0.f, wout = 0.f;
    if (r < H) {
        h1s[r] = 0.f;
        h2s[r] = 0.f;
        const float* xb = x + (b * TT + r) * 1024;   // u[t] = trace(x[b,t]), t = r
        float u = 0.f;
#pragma unroll
        for (int i = 0; i < 32; i++) u += xb[i * 33];
        u_s[r] = u;
        wout = w_out[r];
    }
    __syncthreads();

    for (int t = 0; t < TT; t++) {
        // prefetch first streamed chunk of w_ih1 (constant data — no deps)
        float4 wbuf[8];
#pragma unroll
        for (int j = 0; j < 8; j++) wbuf[j] = wiT4[j * 512 + r];

        // ---- P1: z1 = b0 + wcol*u + w_hh0 @ h1 ; a2h = b1 + w_hh1 @ h2 ----
        float za = fmaf(wcol, u_s[t], bias0), zb = 0.f;
#pragma unroll
        for (int q = 0; q < 16; q++) {
            float4 h = h1s4[q], w = wh0[q];
            za = fmaf(w.x, h.x, za); za = fmaf(w.y, h.y, za);
            za = fmaf(w.z, h.z, za); za = fmaf(w.w, h.w, za);
        }
#pragma unroll
        for (int q = 16; q < 32; q++) {
            float4 h = h1s4[q], w = wh0[q];
            zb = fmaf(w.x, h.x, zb); zb = fmaf(w.y, h.y, zb);
            zb = fmaf(w.z, h.z, zb); zb = fmaf(w.w, h.w, zb);
        }
        float z1 = za + zb;

        float aa = bias1, ab = 0.f;
#pragma unroll
        for (int q = 0; q < 16; q++) {
            float4 h = h2s4[q], w = wh1a[q];
            aa = fmaf(w.x, h.x, aa); aa = fmaf(w.y, h.y, aa);
            aa = fmaf(w.z, h.z, aa); aa = fmaf(w.w, h.w, aa);
        }
#pragma unroll
        for (int q = 0; q < 16; q++) {
            float4 w = whh1b[q * 512 + r];     // own slot — conflict-free b128
            float4 h = h2s4[16 + q];
            ab = fmaf(w.x, h.x, ab); ab = fmaf(w.y, h.y, ab);
            ab = fmaf(w.z, h.z, ab); ab = fmaf(w.w, h.w, ab);
        }
        float a2h = aa + ab;

        // layer-1 activation + tangent seed (dz1/du = wcol), all 512 threads
        float a1, d1;
        if (is_g) { a1 = tanhf_fast(z1); d1 = 1.f - a1 * a1; }
        else      { a1 = sigf(z1);       d1 = a1 * (1.f - a1); }
        act1[r] = a1;
        da1[r]  = d1 * wcol;
        __syncthreads();

        // ---- P2: layer-1 cell update + tangent (threads 0..127) ----
        if (r < H) {
            float i1 = act1[r], f1 = act1[r + 128], g1 = act1[r + 256], o1 = act1[r + 384];
            float di = da1[r], df = da1[r + 128], dg = da1[r + 256], dd = da1[r + 384];
            float dc1 = df * c1 + di * g1 + i1 * dg;    // c1 = c1[t-1]
            c1 = f1 * c1 + i1 * g1;
            float th = tanhf_fast(c1);
            h1s[r] = o1 * th;
            vs[r]  = dd * th + o1 * (1.f - th * th) * dc1;
        }
        __syncthreads();

        // ---- P3: a2 = a2h + w_ih1 @ h1 ; ad = w_ih1 @ v (streamed, dual-use) ----
        float a2 = a2h, ad = 0.f;
#pragma unroll
        for (int c = 0; c < 4; c++) {
#pragma unroll
            for (int j = 0; j < 8; j++) {
                float4 w = wbuf[j];
                if (c < 3) wbuf[j] = wiT4[((c + 1) * 8 + j) * 512 + r];  // 8-deep ahead
                int q = c * 8 + j;
                float4 h  = h1s4[q];
                float4 vv = vs4[q];
                a2 = fmaf(w.x, h.x, a2);  a2 = fmaf(w.y, h.y, a2);
                a2 = fmaf(w.z, h.z, a2);  a2 = fmaf(w.w, h.w, a2);
                ad = fmaf(w.x, vv.x, ad); ad = fmaf(w.y, vv.y, ad);
                ad = fmaf(w.z, vv.z, ad); ad = fmaf(w.w, vv.w, ad);
            }
        }
        // layer-2 activation + tangent (dz2/du = ad), all 512 threads
        float a2a, d2;
        if (is_g) { a2a = tanhf_fast(a2); d2 = 1.f - a2a * a2a; }
        else      { a2a = sigf(a2);       d2 = a2a * (1.f - a2a); }
        act2[r] = a2a;
        t2[r]   = d2 * ad;
        __syncthreads();

        // ---- P4: layer-2 cell update + output tangent (threads 0..127) ----
        if (r < H) {
            float i2 = act2[r], f2 = act2[r + 128], g2 = act2[r + 256], o2 = act2[r + 384];
            float di = t2[r], df = t2[r + 128], dg = t2[r + 256], dd = t2[r + 384];
            float dc2 = df * c2 + di * g2 + i2 * dg;    // c2 = c2[t-1]
            c2 = f2 * c2 + i2 * g2;
            float th = tanhf_fast(c2);
            h2s[r] = o2 * th;
            float dh2 = dd * th + o2 * (1.f - th * th) * dc2;
            float p = wout * dh2;
#pragma unroll
            for (int d = 32; d > 0; d >>= 1) p += __shfl_down(p, d, 64);
            if ((r & 63) == 0) red[r >> 6] = p;
        }
        __syncthreads();
        if (r == 0) gbuf[b * TT + t] = red[0] + red[1];
        // red next written in P4 of t+1, after 3 more barriers — no race
    }
}

// ---------------------------------------------------------------------------
// fill: out[b,t,i,j] = (i==j) ? g[b,t] : 0  over the full 4 MB output.
// ---------------------------------------------------------------------------
__global__ void fill_kernel(const float* __restrict__ gbuf,
                            float4* __restrict__ out4) {
    int id   = blockIdx.x * 256 + threadIdx.x;  // 0 .. 262143
    int base = id * 4;
    int j0   = base & 31;
    int i    = (base >> 5) & 31;
    int bt   = base >> 10;                      // 0 .. 1023
    float g  = gbuf[bt];
    float4 v;
    v.x = (j0     == i) ? g : 0.f;
    v.y = (j0 + 1 == i) ? g : 0.f;
    v.z = (j0 + 2 == i) ? g : 0.f;
    v.w = (j0 + 3 == i) ? g : 0.f;
    out4[id] = v;
}

extern "C" void kernel_launch(void* const* d_in, const int* in_sizes, int n_in,
                              void* d_out, int out_size, void* d_ws, size_t ws_size,
                              hipStream_t stream) {
    const float* x     = (const float*)d_in[0];
    const float* w_ih0 = (const float*)d_in[1];
    const float* w_hh0 = (const float*)d_in[2];
    const float* b_ih0 = (const float*)d_in[3];
    const float* b_hh0 = (const float*)d_in[4];
    const float* w_ih1 = (const float*)d_in[5];
    const float* w_hh1 = (const float*)d_in[6];
    const float* b_ih1 = (const float*)d_in[7];
    const float* b_hh1 = (const float*)d_in[8];
    const float* w_out = (const float*)d_in[9];
    // d_in[10] = b_out: constant offset, zero derivative -> unused

    float4* ws4  = (float4*)d_ws;
    float4* wiT4 = ws4;                         // 16384 f4 = 256 KB
    float4* whT4 = ws4 + 16384;                 //  8192 f4 = 128 KB
    float*  gbuf = (float*)(ws4 + 24576);       //  1024 floats

    prep_kernel<<<dim3(96), dim3(256), 0, stream>>>(w_ih1, w_hh1, ws4);
    lstm_kernel<<<dim3(BB), dim3(512), 0, stream>>>(x, w_ih0, w_hh0, w_hh1,
                                                    b_ih0, b_hh0, b_ih1, b_hh1, w_out,
                                                    wiT4, whT4, gbuf);
    fill_kernel<<<dim3(1024), dim3(256), 0, stream>>>(gbuf, (float4*)d_out);
}

// Round 3
// 297.717 us; speedup vs baseline: 8.2409x; 8.2409x over previous
//
#include <hip/hip_runtime.h>
#include <math.h>

#define H    128
#define TT   128
#define BB   8
#define CH   8            // steps per flag (chunk)
#define NCH  (TT / CH)    // 16 chunks
#define RD   4            // part-ring depth in chunks

// ws layout (float offsets)
#define OFF_H1V   0                     // [b][t][256]            : 262144 floats
#define OFF_PART  262144                // [b][slot RD][CH][1024] : 262144 floats
#define OFF_CNT   524288                // int counters, 64B-strided
#define OFF_GBUF  (524288 + 512)        // [b][t] g               : 1024 floats

__device__ __forceinline__ float sigf(float x)       { return 1.0f / (1.0f + __expf(-x)); }
__device__ __forceinline__ float tanhf_fast(float x) { return 1.0f - 2.0f / (1.0f + __expf(2.0f * x)); }

// ---------------------------------------------------------------------------
// 3-stage per-batch CU pipeline. blockIdx: [0..7]=A(layer1), [8..15]=B(w_ih1
// dots), [16..23]=C(w_hh1 + elementwise + output). Each stage holds its
// 512x128 weight matrix fully in registers (32 float4/thread). Handoff via
// ws ring buffers + chunked agent-scope counters (cross-XCD safe).
// ---------------------------------------------------------------------------
__global__ __launch_bounds__(512, 1)
void lstm3_kernel(const float* __restrict__ x,
                  const float* __restrict__ w_ih0,
                  const float* __restrict__ w_hh0,
                  const float* __restrict__ b_ih0,
                  const float* __restrict__ b_hh0,
                  const float* __restrict__ w_ih1,
                  const float* __restrict__ w_hh1,
                  const float* __restrict__ b_ih1,
                  const float* __restrict__ b_hh1,
                  const float* __restrict__ w_out,
                  float* __restrict__ ws) {
    const int role = blockIdx.x >> 3;
    const int b    = blockIdx.x & 7;
    const int r    = threadIdx.x;

    int* cntA = (int*)ws + OFF_CNT       + b * 16;
    int* cntB = (int*)ws + OFF_CNT + 128 + b * 16;
    int* cntC = (int*)ws + OFF_CNT + 256 + b * 16;
    float* h1v  = ws + OFF_H1V  + b * TT * 256;
    float* part = ws + OFF_PART + b * RD * CH * 1024;

    __shared__ float4 hs4[32];            // state vector (A: h1, C: h2)
    __shared__ float  u_s[TT];            // A only
    __shared__ float  e1[512], e2[512];   // activation / tangent staging
    __shared__ float  red[2];
    __shared__ float4 h1c4[CH * 32];      // B: chunk of h1
    __shared__ float4 vc4[CH * 32];       // B: chunk of v
    float* hs = (float*)hs4;

    const bool is_g = (r >= 256) && (r < 384);   // wave-uniform

    if (role == 0) {
        // ================= Stage A: layer-1 forward + tangent =================
        float4 wr[32];
        const float4* p = reinterpret_cast<const float4*>(w_hh0 + r * H);
#pragma unroll
        for (int q = 0; q < 32; q++) wr[q] = p[q];
        const float wcol = w_ih0[r];
        const float bias = b_ih0[r] + b_hh0[r];
        if (r < H) {
            hs[r] = 0.f;
            const float* xb = x + (b * TT + r) * 1024;   // u[t]=trace(x[b,t]), t=r
            float u = 0.f;
#pragma unroll
            for (int i = 0; i < 32; i++) u += xb[i * 33];
            u_s[r] = u;
        }
        __syncthreads();
        float c1 = 0.f;
        for (int t = 0; t < TT; t++) {
            float z = fmaf(wcol, u_s[t], bias);
#pragma unroll
            for (int q = 0; q < 32; q++) {
                float4 h = hs4[q], w = wr[q];
                z = fmaf(w.x, h.x, z); z = fmaf(w.y, h.y, z);
                z = fmaf(w.z, h.z, z); z = fmaf(w.w, h.w, z);
            }
            float a, d;
            if (is_g) { a = tanhf_fast(z); d = 1.f - a * a; }
            else      { a = sigf(z);       d = a * (1.f - a); }
            e1[r] = a; e2[r] = d * wcol;
            __syncthreads();
            if (r < H) {
                float i1 = e1[r], f1 = e1[r + 128], g1 = e1[r + 256], o1 = e1[r + 384];
                float di = e2[r], df = e2[r + 128], dg = e2[r + 256], dd = e2[r + 384];
                float dc = df * c1 + di * g1 + i1 * dg;
                c1 = f1 * c1 + i1 * g1;
                float th = tanhf_fast(c1);
                float hn = o1 * th;
                float vn = dd * th + o1 * (1.f - th * th) * dc;
                hs[r] = hn;
                h1v[t * 256 + r]       = hn;
                h1v[t * 256 + 128 + r] = vn;
            }
            __syncthreads();
            if ((t & (CH - 1)) == CH - 1) {
                __threadfence();
                if (r == 0)
                    __hip_atomic_store(cntA, t + 1, __ATOMIC_RELEASE, __HIP_MEMORY_SCOPE_AGENT);
            }
        }
    } else if (role == 1) {
        // ================= Stage B: w_ih1 @ h1 and w_ih1 @ v =================
        float4 wr[32];
        const float4* p = reinterpret_cast<const float4*>(w_ih1 + r * H);
#pragma unroll
        for (int q = 0; q < 32; q++) wr[q] = p[q];
        for (int c = 0; c < NCH; c++) {
            if (r == 0) {
                while (__hip_atomic_load(cntA, __ATOMIC_ACQUIRE, __HIP_MEMORY_SCOPE_AGENT) < (c + 1) * CH)
                    __builtin_amdgcn_s_sleep(2);
                if (c >= RD)   // ring backpressure: C must have consumed slot
                    while (__hip_atomic_load(cntC, __ATOMIC_ACQUIRE, __HIP_MEMORY_SCOPE_AGENT) < (c - (RD - 1)) * CH)
                        __builtin_amdgcn_s_sleep(2);
            }
            __syncthreads();
            {   // stage chunk of h1/v into LDS (512 float4, 1 per thread)
                const float4* src = reinterpret_cast<const float4*>(h1v + c * CH * 256);
                float4 vd = src[r];
                int tl = r >> 6, j = r & 63;
                if (j < 32) h1c4[tl * 32 + j] = vd;
                else        vc4[tl * 32 + j - 32] = vd;
            }
            __syncthreads();
            float* pslot = part + (c & (RD - 1)) * CH * 1024;
            for (int tl = 0; tl < CH; tl++) {
                float z = 0.f, a = 0.f;
#pragma unroll
                for (int q = 0; q < 32; q++) {
                    float4 w = wr[q];
                    float4 h = h1c4[tl * 32 + q];
                    float4 v = vc4[tl * 32 + q];
                    z = fmaf(w.x, h.x, z); z = fmaf(w.y, h.y, z);
                    z = fmaf(w.z, h.z, z); z = fmaf(w.w, h.w, z);
                    a = fmaf(w.x, v.x, a); a = fmaf(w.y, v.y, a);
                    a = fmaf(w.z, v.z, a); a = fmaf(w.w, v.w, a);
                }
                pslot[tl * 1024 + r]       = z;
                pslot[tl * 1024 + 512 + r] = a;
            }
            __threadfence();
            if (r == 0)
                __hip_atomic_store(cntB, (c + 1) * CH, __ATOMIC_RELEASE, __HIP_MEMORY_SCOPE_AGENT);
        }
    } else {
        // ========== Stage C: w_hh1 @ h2 + layer-2 elementwise + output ==========
        float4 wr[32];
        const float4* p = reinterpret_cast<const float4*>(w_hh1 + r * H);
#pragma unroll
        for (int q = 0; q < 32; q++) wr[q] = p[q];
        const float bias = b_ih1[r] + b_hh1[r];
        const float wout = (r < H) ? w_out[r] : 0.f;
        if (r < H) hs[r] = 0.f;
        __syncthreads();
        float c2 = 0.f;
        float* gbuf = ws + OFF_GBUF;
        for (int c = 0; c < NCH; c++) {
            if (r == 0)
                while (__hip_atomic_load(cntB, __ATOMIC_ACQUIRE, __HIP_MEMORY_SCOPE_AGENT) < (c + 1) * CH)
                    __builtin_amdgcn_s_sleep(2);
            __syncthreads();
            const float* pslot = part + (c & (RD - 1)) * CH * 1024;
            for (int tl = 0; tl < CH; tl++) {
                const int t = c * CH + tl;
                float z2i = pslot[tl * 1024 + r];        // issue early, overlap dot
                float adi = pslot[tl * 1024 + 512 + r];
                float z = bias;
#pragma unroll
                for (int q = 0; q < 32; q++) {
                    float4 h = hs4[q], w = wr[q];
                    z = fmaf(w.x, h.x, z); z = fmaf(w.y, h.y, z);
                    z = fmaf(w.z, h.z, z); z = fmaf(w.w, h.w, z);
                }
                z += z2i;
                float a, d;
                if (is_g) { a = tanhf_fast(z); d = 1.f - a * a; }
                else      { a = sigf(z);       d = a * (1.f - a); }
                e1[r] = a; e2[r] = d * adi;
                __syncthreads();
                if (r < H) {
                    float i2 = e1[r], f2 = e1[r + 128], g2 = e1[r + 256], o2 = e1[r + 384];
                    float di = e2[r], df = e2[r + 128], dg = e2[r + 256], dd = e2[r + 384];
                    float dc = df * c2 + di * g2 + i2 * dg;
                    c2 = f2 * c2 + i2 * g2;
                    float th = tanhf_fast(c2);
                    hs[r] = o2 * th;
                    float dh2 = dd * th + o2 * (1.f - th * th) * dc;
                    float pp = wout * dh2;
#pragma unroll
                    for (int s = 32; s > 0; s >>= 1) pp += __shfl_down(pp, s, 64);
                    if ((r & 63) == 0) red[r >> 6] = pp;
                }
                __syncthreads();
                if (r == 0) gbuf[b * TT + t] = red[0] + red[1];
                // red next written after next step's act barrier — no race
            }
            __threadfence();
            if (r == 0)
                __hip_atomic_store(cntC, (c + 1) * CH, __ATOMIC_RELEASE, __HIP_MEMORY_SCOPE_AGENT);
        }
    }
}

// ---------------------------------------------------------------------------
// fill: out[b,t,i,j] = (i==j) ? g[b,t] : 0  over the full 4 MB output.
// ---------------------------------------------------------------------------
__global__ void fill_kernel(const float* __restrict__ gbuf,
                            float4* __restrict__ out4) {
    int id   = blockIdx.x * 256 + threadIdx.x;  // 0 .. 262143
    int base = id * 4;
    int j0   = base & 31;
    int i    = (base >> 5) & 31;
    int bt   = base >> 10;                      // 0 .. 1023
    float g  = gbuf[bt];
    float4 v;
    v.x = (j0     == i) ? g : 0.f;
    v.y = (j0 + 1 == i) ? g : 0.f;
    v.z = (j0 + 2 == i) ? g : 0.f;
    v.w = (j0 + 3 == i) ? g : 0.f;
    out4[id] = v;
}

extern "C" void kernel_launch(void* const* d_in, const int* in_sizes, int n_in,
                              void* d_out, int out_size, void* d_ws, size_t ws_size,
                              hipStream_t stream) {
    const float* x     = (const float*)d_in[0];
    const float* w_ih0 = (const float*)d_in[1];
    const float* w_hh0 = (const float*)d_in[2];
    const float* b_ih0 = (const float*)d_in[3];
    const float* b_hh0 = (const float*)d_in[4];
    const float* w_ih1 = (const float*)d_in[5];
    const float* w_hh1 = (const float*)d_in[6];
    const float* b_ih1 = (const float*)d_in[7];
    const float* b_hh1 = (const float*)d_in[8];
    const float* w_out = (const float*)d_in[9];
    // d_in[10] = b_out: constant offset, zero derivative -> unused

    float* ws = (float*)d_ws;   // needs ~2.1 MB; counters rely on 0xAA poison (<0 as int)

    lstm3_kernel<<<dim3(24), dim3(512), 0, stream>>>(x, w_ih0, w_hh0, b_ih0, b_hh0,
                                                     w_ih1, w_hh1, b_ih1, b_hh1, w_out,
                                                     ws);
    fill_kernel<<<dim3(1024), dim3(256), 0, stream>>>(ws + OFF_GBUF, (float4*)d_out);
}